// Round 8
// baseline (30.720 us; speedup 1.0000x reference)
//
#include <hip/hip_runtime.h>

// Problem constants (must match reference)
constexpr int kBImg   = 16384;
constexpr int kG      = 7;
constexpr int kCh     = 30;            // 5*NB + CLS
constexpr int kT      = kBImg * 8;     // 131072 targets
constexpr int kNCells = kBImg * kG * kG;    // 802,816 cells
constexpr int kNF4    = kNCells * kCh / 4;  // 6,021,120 float4s
constexpr int kThreads = 256;

// Phase A: full coalesced float4 stream, 8 independent loads per thread
constexpr int kBlocksA  = 2940;
constexpr int kThrA     = kBlocksA * kThreads;  // 752,640
constexpr int kF4PerThr = kNF4 / kThrA;         // 8 (exact)
static_assert(kF4PerThr * kThrA == kNF4, "exact cover");
// 4*kThrA % 30 == 0  (752,640 divisible by 15) -> residue invariant across j
static_assert((4ll * kThrA) % 30 == 0, "residue invariant");

// Phase B: one thread per target
constexpr int kBlocksB = kT / kThreads;          // 512 (exact)
constexpr int kBlocksTot = kBlocksA + kBlocksB;  // 3452

__global__ void loss_init(float* __restrict__ outv) {
    outv[0] = 0.f;
}

__global__ __launch_bounds__(kThreads)
void loss_main(const float* __restrict__ outp,
               const float* __restrict__ tgt,
               float* __restrict__ partial,   // nullptr -> atomic fallback
               float* __restrict__ outv) {
    float acc = 0.f;

    if (blockIdx.x < kBlocksA) {
        // ---- Phase A: lambda_noobj * c^2 over channels 4 and 9 of every cell.
        // Pure streaming: thread handles float4 indices tid + j*kThrA (j=0..7),
        // all 8 loads independent and fully coalesced. Residue
        // r = (4*idx) % 30 is the same for all j (4*kThrA % 30 == 0):
        //   r==2 -> .z (ch4); r==4 -> .x (ch4); r==6 -> .w (ch9); r==8 -> .y (ch9)
        const int tid = blockIdx.x * kThreads + threadIdx.x;
        const float4* o4 = reinterpret_cast<const float4*>(outp);
        float4 c[kF4PerThr];
        #pragma unroll
        for (int j = 0; j < kF4PerThr; ++j) c[j] = o4[tid + j * kThrA];

        unsigned r = (4u * (unsigned)tid) % 30u;
        bool s2 = (r == 2u), s4 = (r == 4u), s6 = (r == 6u), s8 = (r == 8u);
        #pragma unroll
        for (int j = 0; j < kF4PerThr; ++j) {
            float v = s2 ? c[j].z
                    : s4 ? c[j].x
                    : s6 ? c[j].w
                    : s8 ? c[j].y : 0.f;
            acc += 0.5f * v * v;   // LAMBDA_NOOBJ = 0.5
        }
    } else {
        // ---- Phase B: one target per thread.
        // Target row = 8 floats: {x, y, w, h, gx, gy, cls, bid}
        const int btid = (blockIdx.x - kBlocksA) * kThreads + threadIdx.x;
        const float4* t4 = reinterpret_cast<const float4*>(tgt);
        float4 ta = t4[2 * btid];       // x, y, w, h
        float4 tb = t4[2 * btid + 1];   // gx, gy, cls, bid
        float x_t = ta.x, y_t = ta.y, w_t = ta.z, h_t = ta.w;
        int gx    = (int)tb.x;
        int gy    = (int)tb.y;
        int cls_t = (int)tb.z;
        int bid   = (int)tb.w;

        // Cell base: 30 floats = 120 bytes -> always 8B aligned, use float2.
        const float2* gf2 = reinterpret_cast<const float2*>(
            outp + ((bid * kG + gx) * kG + gy) * kCh);

        // 15 independent float2 loads, all statically indexed.
        float2 p0 = gf2[0], p1 = gf2[1], p2 = gf2[2], p3 = gf2[3], p4 = gf2[4];
        float2 q[10];
        #pragma unroll
        for (int jj = 0; jj < 10; ++jj) q[jj] = gf2[5 + jj];

        float x0 = p0.x, y0 = p0.y, w0 = p1.x, h0 = p1.y, c0 = p2.x;
        float x1 = p2.y, y1 = p3.x, w1 = p3.y, h1 = p4.x, c1 = p4.y;

        float top_t   = y_t - 3.5f * h_t, bot_t   = y_t + 3.5f * h_t;
        float left_t  = x_t - 3.5f * w_t, right_t = x_t + 3.5f * w_t;
        float area_t  = w_t * h_t * 49.f;

        // box 0
        float wi0 = fmaxf(fminf(x0 + 3.5f*w0, right_t) - fmaxf(x0 - 3.5f*w0, left_t), 0.f);
        float hi0 = fmaxf(fmaxf(y0 - 3.5f*h0, top_t)   - fminf(y0 + 3.5f*h0, bot_t), 0.f);
        float ai0 = wi0 * hi0;
        float at0 = area_t + w0 * h0 * 49.f - ai0;
        float iou0 = (at0 > 0.f) ? (ai0 / at0) : 0.f;

        // box 1
        float wi1 = fmaxf(fminf(x1 + 3.5f*w1, right_t) - fmaxf(x1 - 3.5f*w1, left_t), 0.f);
        float hi1 = fmaxf(fmaxf(y1 - 3.5f*h1, top_t)   - fminf(y1 + 3.5f*h1, bot_t), 0.f);
        float ai1 = wi1 * hi1;
        float at1 = area_t + w1 * h1 * 49.f - ai1;
        float iou1 = (at1 > 0.f) ? (ai1 / at1) : 0.f;

        // argmax with first-max-wins tie rule (jnp.argmax)
        bool pick1 = (iou1 > iou0);
        float x_r = pick1 ? x1 : x0;
        float y_r = pick1 ? y1 : y0;
        float w_r = pick1 ? w1 : w0;
        float h_r = pick1 ? h1 : h0;
        float c_r = pick1 ? c1 : c0;

        float dx = x_t - x_r, dy = y_t - y_r;
        float dw = sqrtf(w_t) - sqrtf(w_r);
        float dh = sqrtf(h_t) - sqrtf(h_r);
        acc += 5.f * (dx*dx + dy*dy + dw*dw + dh*dh);      // LAMBDA_COORD
        acc += (c_r - 1.f) * (c_r - 1.f) - 0.5f * c_r * c_r;

        // class terms: sum of squares + gathered class, all static indices
        float s = 0.f, clr = 0.f;
        #pragma unroll
        for (int jj = 0; jj < 10; ++jj) {
            s += q[jj].x * q[jj].x + q[jj].y * q[jj].y;
            clr = (cls_t == 2 * jj)     ? q[jj].x : clr;
            clr = (cls_t == 2 * jj + 1) ? q[jj].y : clr;
        }
        acc += s;
        acc += (clr - 1.f) * (clr - 1.f) - clr * clr;
    }

    // ---- Deterministic block reduction ----
    __shared__ float sm[kThreads];
    sm[threadIdx.x] = acc;
    __syncthreads();
    for (int s = kThreads / 2; s > 0; s >>= 1) {
        if (threadIdx.x < s) sm[threadIdx.x] += sm[threadIdx.x + s];
        __syncthreads();
    }
    if (threadIdx.x == 0) {
        if (partial) {
            partial[blockIdx.x] = sm[0];               // no atomics
        } else {
            atomicAdd(outv, sm[0] * (1.f / (float)kBImg));  // fallback
        }
    }
}

__global__ __launch_bounds__(kThreads)
void loss_reduce(const float* __restrict__ partial, float* __restrict__ outv) {
    __shared__ float sm[kThreads];
    float a = 0.f;
    for (int i = threadIdx.x; i < kBlocksTot; i += kThreads) a += partial[i];
    sm[threadIdx.x] = a;
    __syncthreads();
    for (int s = kThreads / 2; s > 0; s >>= 1) {
        if (threadIdx.x < s) sm[threadIdx.x] += sm[threadIdx.x + s];
        __syncthreads();
    }
    if (threadIdx.x == 0) outv[0] = sm[0] * (1.f / (float)kBImg);
}

extern "C" void kernel_launch(void* const* d_in, const int* in_sizes, int n_in,
                              void* d_out, int out_size, void* d_ws, size_t ws_size,
                              hipStream_t stream) {
    const float* outp = (const float*)d_in[0];   // (16384,7,7,30) f32
    const float* tgt  = (const float*)d_in[1];   // (131072,8) f32
    float* outv       = (float*)d_out;

    const bool use_ws = (d_ws != nullptr) && (ws_size >= (size_t)kBlocksTot * sizeof(float));
    float* partial = use_ws ? (float*)d_ws : nullptr;

    if (use_ws) {
        loss_main<<<kBlocksTot, kThreads, 0, stream>>>(outp, tgt, partial, outv);
        loss_reduce<<<1, kThreads, 0, stream>>>(partial, outv);
    } else {
        loss_init<<<1, 1, 0, stream>>>(outv);
        loss_main<<<kBlocksTot, kThreads, 0, stream>>>(outp, tgt, nullptr, outv);
    }
}

// Round 9
// 29.530 us; speedup vs baseline: 1.0403x; 1.0403x over previous
//
#include <hip/hip_runtime.h>

// Problem constants (must match reference)
constexpr int kBImg   = 16384;
constexpr int kG      = 7;
constexpr int kCh     = 30;            // 5*NB + CLS
constexpr int kT      = kBImg * 8;     // 131072 targets
constexpr int kNCells = kBImg * kG * kG;    // 802,816 cells
constexpr int kNF4    = kNCells * kCh / 4;  // 6,021,120 float4s
constexpr int kThreads = 256;

// ---- Phase A geometry: 960B period = 8 cells = 60 float4s = 15 lines.
// Confidence dwords (ch4/ch9 of each cell) occupy 10 lines = 40 float4s:
// lines {0,2,4,5,6,7,8,9,11,13}. We read exactly those 40 f4s per period.
constexpr int kPeriods   = kNCells / 8;        // 100,352
constexpr int kNU        = kPeriods * 40;      // 4,014,080 useful float4s
constexpr int kF4PerThrA = 8;
constexpr int kThrA      = kNU / kF4PerThrA;   // 501,760
constexpr int kBlocksA   = kThrA / kThreads;   // 1960 (exact)
constexpr int kPStep     = kThrA / 40;         // 12,544 periods per j-step
static_assert(kBlocksA * kThreads == kThrA, "exact");
static_assert(kThrA % 40 == 0, "slot invariant across j");

// Phase B: one thread per target
constexpr int kBlocksB   = kT / kThreads;          // 512 (exact)
constexpr int kBlocksTot = kBlocksA + kBlocksB;    // 2472

__global__ void loss_init(float* __restrict__ outv) {
    outv[0] = 0.f;
}

__global__ __launch_bounds__(kThreads)
void loss_main(const float* __restrict__ outp,
               const float* __restrict__ tgt,
               float* __restrict__ partial,   // nullptr -> atomic fallback
               float* __restrict__ outv) {
    float acc = 0.f;

    if (blockIdx.x < kBlocksA) {
        // ---- Phase A: lambda_noobj * c^2, cooperative full-line gather.
        // rank r = tid + j*kThrA owns useful-f4 #r: period p = r/40, slot
        // k = r%40. kThrA%40==0 -> k (and line/q/residue) is j-invariant.
        const int tid = blockIdx.x * kThreads + threadIdx.x;
        const int k   = tid % 40;
        const int p0  = tid / 40;
        const int m   = k >> 2;       // useful-line index 0..9
        const int q   = k & 3;        // float4 within line
        // line = {0,2,4,5,6,7,8,9,11,13}[m], branchless
        const int line = (m == 0) ? 0 : (m == 1) ? 2
                       : (m <= 7) ? (m + 2) : (m == 8) ? 11 : 13;
        // residue of this float4's first float within the 30-float cell
        const int r0 = (16 * line + 4 * q) % 30;
        // element holding a confidence (ch4: r0==4-e ; ch9: r0==9-e), <=1 per f4
        const bool e0 = (r0 == 4) || (r0 == 9);
        const bool e1 = (r0 == 3) || (r0 == 8);
        const bool e2 = (r0 == 2) || (r0 == 7);
        const bool e3 = (r0 == 1) || (r0 == 6);

        const float4* o4 = reinterpret_cast<const float4*>(outp) + line * 4 + q;
        float4 c[kF4PerThrA];
        #pragma unroll
        for (int j = 0; j < kF4PerThrA; ++j)
            c[j] = o4[(p0 + j * kPStep) * 60];
        #pragma unroll
        for (int j = 0; j < kF4PerThrA; ++j) {
            float v = e0 ? c[j].x : e1 ? c[j].y : e2 ? c[j].z : e3 ? c[j].w : 0.f;
            acc += 0.5f * v * v;   // LAMBDA_NOOBJ = 0.5
        }
    } else {
        // ---- Phase B: one target per thread.
        // Target row = 8 floats: {x, y, w, h, gx, gy, cls, bid}
        const int btid = (blockIdx.x - kBlocksA) * kThreads + threadIdx.x;
        const float4* t4 = reinterpret_cast<const float4*>(tgt);
        float4 ta = t4[2 * btid];       // x, y, w, h
        float4 tb = t4[2 * btid + 1];   // gx, gy, cls, bid
        float x_t = ta.x, y_t = ta.y, w_t = ta.z, h_t = ta.w;
        int gx    = (int)tb.x;
        int gy    = (int)tb.y;
        int cls_t = (int)tb.z;
        int bid   = (int)tb.w;

        // Cell base: 30 floats = 120 bytes -> always 8B aligned, use float2.
        const float2* gf2 = reinterpret_cast<const float2*>(
            outp + ((bid * kG + gx) * kG + gy) * kCh);

        // 15 independent float2 loads, all statically indexed.
        float2 p0 = gf2[0], p1 = gf2[1], p2 = gf2[2], p3 = gf2[3], p4 = gf2[4];
        float2 q[10];
        #pragma unroll
        for (int jj = 0; jj < 10; ++jj) q[jj] = gf2[5 + jj];

        float x0 = p0.x, y0 = p0.y, w0 = p1.x, h0 = p1.y, c0 = p2.x;
        float x1 = p2.y, y1 = p3.x, w1 = p3.y, h1 = p4.x, c1 = p4.y;

        float top_t   = y_t - 3.5f * h_t, bot_t   = y_t + 3.5f * h_t;
        float left_t  = x_t - 3.5f * w_t, right_t = x_t + 3.5f * w_t;
        float area_t  = w_t * h_t * 49.f;

        // box 0
        float wi0 = fmaxf(fminf(x0 + 3.5f*w0, right_t) - fmaxf(x0 - 3.5f*w0, left_t), 0.f);
        float hi0 = fmaxf(fmaxf(y0 - 3.5f*h0, top_t)   - fminf(y0 + 3.5f*h0, bot_t), 0.f);
        float ai0 = wi0 * hi0;
        float at0 = area_t + w0 * h0 * 49.f - ai0;
        float iou0 = (at0 > 0.f) ? (ai0 / at0) : 0.f;

        // box 1
        float wi1 = fmaxf(fminf(x1 + 3.5f*w1, right_t) - fmaxf(x1 - 3.5f*w1, left_t), 0.f);
        float hi1 = fmaxf(fmaxf(y1 - 3.5f*h1, top_t)   - fminf(y1 + 3.5f*h1, bot_t), 0.f);
        float ai1 = wi1 * hi1;
        float at1 = area_t + w1 * h1 * 49.f - ai1;
        float iou1 = (at1 > 0.f) ? (ai1 / at1) : 0.f;

        // argmax with first-max-wins tie rule (jnp.argmax)
        bool pick1 = (iou1 > iou0);
        float x_r = pick1 ? x1 : x0;
        float y_r = pick1 ? y1 : y0;
        float w_r = pick1 ? w1 : w0;
        float h_r = pick1 ? h1 : h0;
        float c_r = pick1 ? c1 : c0;

        float dx = x_t - x_r, dy = y_t - y_r;
        float dw = sqrtf(w_t) - sqrtf(w_r);
        float dh = sqrtf(h_t) - sqrtf(h_r);
        acc += 5.f * (dx*dx + dy*dy + dw*dw + dh*dh);      // LAMBDA_COORD
        acc += (c_r - 1.f) * (c_r - 1.f) - 0.5f * c_r * c_r;

        // class terms: sum of squares + gathered class, all static indices
        float s = 0.f, clr = 0.f;
        #pragma unroll
        for (int jj = 0; jj < 10; ++jj) {
            s += q[jj].x * q[jj].x + q[jj].y * q[jj].y;
            clr = (cls_t == 2 * jj)     ? q[jj].x : clr;
            clr = (cls_t == 2 * jj + 1) ? q[jj].y : clr;
        }
        acc += s;
        acc += (clr - 1.f) * (clr - 1.f) - clr * clr;
    }

    // ---- Deterministic block reduction ----
    __shared__ float sm[kThreads];
    sm[threadIdx.x] = acc;
    __syncthreads();
    for (int s = kThreads / 2; s > 0; s >>= 1) {
        if (threadIdx.x < s) sm[threadIdx.x] += sm[threadIdx.x + s];
        __syncthreads();
    }
    if (threadIdx.x == 0) {
        if (partial) {
            partial[blockIdx.x] = sm[0];               // no atomics
        } else {
            atomicAdd(outv, sm[0] * (1.f / (float)kBImg));  // fallback
        }
    }
}

__global__ __launch_bounds__(kThreads)
void loss_reduce(const float* __restrict__ partial, float* __restrict__ outv) {
    __shared__ float sm[kThreads];
    float a = 0.f;
    for (int i = threadIdx.x; i < kBlocksTot; i += kThreads) a += partial[i];
    sm[threadIdx.x] = a;
    __syncthreads();
    for (int s = kThreads / 2; s > 0; s >>= 1) {
        if (threadIdx.x < s) sm[threadIdx.x] += sm[threadIdx.x + s];
        __syncthreads();
    }
    if (threadIdx.x == 0) outv[0] = sm[0] * (1.f / (float)kBImg);
}

extern "C" void kernel_launch(void* const* d_in, const int* in_sizes, int n_in,
                              void* d_out, int out_size, void* d_ws, size_t ws_size,
                              hipStream_t stream) {
    const float* outp = (const float*)d_in[0];   // (16384,7,7,30) f32
    const float* tgt  = (const float*)d_in[1];   // (131072,8) f32
    float* outv       = (float*)d_out;

    const bool use_ws = (d_ws != nullptr) && (ws_size >= (size_t)kBlocksTot * sizeof(float));
    float* partial = use_ws ? (float*)d_ws : nullptr;

    if (use_ws) {
        loss_main<<<kBlocksTot, kThreads, 0, stream>>>(outp, tgt, partial, outv);
        loss_reduce<<<1, kThreads, 0, stream>>>(partial, outv);
    } else {
        loss_init<<<1, 1, 0, stream>>>(outv);
        loss_main<<<kBlocksTot, kThreads, 0, stream>>>(outp, tgt, nullptr, outv);
    }
}